// Round 10
// baseline (1415.433 us; speedup 1.0000x reference)
//
#include <hip/hip_runtime.h>
#include <hip/hip_bf16.h>

#define N_TOK 8192
#define DIM   1024
#define HID   4096
#define NEXP  8
#define TOPK  2
#define M_TOT (N_TOK*TOPK)
#define NBLK  1024   // 4 blocks/CU x 256 CUs; NBLK % 8 == 0 (XCD residue preserved)

typedef __bf16 bf16x8 __attribute__((ext_vector_type(8)));
typedef float  f32x4  __attribute__((ext_vector_type(4)));

__device__ __forceinline__ unsigned short f2bf(float f) {
    union { __hip_bfloat16 h; unsigned short u; } c;
    c.h = __float2bfloat16(f);
    return c.u;
}

// async global->LDS, 16B/lane. LDS dest wave-uniform base; lane l -> base + l*16B.
__device__ __forceinline__ void gload16(const unsigned short* g, unsigned short* l) {
    __builtin_amdgcn_global_load_lds(
        (const __attribute__((address_space(1))) void*)g,
        (__attribute__((address_space(3))) void*)l,
        16, 0, 0);
}

// ---------------------------------------------------------------------------
// 128x128 tile, BK=32, 4 waves (each 64x64 = 4x4 frags of 16x16x32 MFMA).
// Double-buffered LDS (2 x 8KB per operand), stage-early 2-phase.
// LDS granule swizzle verified conflict-free + correct (R8/R9: BANK_CONFLICT=0).
// ---------------------------------------------------------------------------
template<int KTOT>
__device__ __forceinline__ void kloop(
    const unsigned short* __restrict__ aG0, const unsigned short* __restrict__ aG1,
    const unsigned short* __restrict__ bG0, const unsigned short* __restrict__ bG1,
    unsigned short* As, unsigned short* Bs,
    unsigned short* asD0, unsigned short* asD1,
    unsigned short* bsD0, unsigned short* bsD1,
    int wr, int wc, int fr, int g0,
    f32x4 (&acc)[4][4])
{
#define STG(B, K) \
    gload16(aG0 + (K), asD0 + (B)*4096); \
    gload16(aG1 + (K), asD1 + (B)*4096); \
    gload16(bG0 + (K), bsD0 + (B)*4096); \
    gload16(bG1 + (K), bsD1 + (B)*4096)

    STG(0, 0);
    asm volatile("s_waitcnt vmcnt(0)" ::: "memory");
    __builtin_amdgcn_s_barrier();

#pragma unroll 1
    for (int k0 = 0; k0 < KTOT; k0 += 64) {
        // phase A: compute buf0 (k0); prefetch k0+32 -> buf1
        STG(1, k0 + 32);
        {
            bf16x8 af[4], bfr[4];
#pragma unroll
            for (int m = 0; m < 4; ++m) af[m]  = *(const bf16x8*)&As[(wr + m*16 + fr)*32 + g0];
#pragma unroll
            for (int n = 0; n < 4; ++n) bfr[n] = *(const bf16x8*)&Bs[(wc + n*16 + fr)*32 + g0];
            __builtin_amdgcn_s_setprio(1);
#pragma unroll
            for (int m = 0; m < 4; ++m)
#pragma unroll
                for (int n = 0; n < 4; ++n)
                    acc[m][n] = __builtin_amdgcn_mfma_f32_16x16x32_bf16(af[m], bfr[n], acc[m][n], 0, 0, 0);
            __builtin_amdgcn_s_setprio(0);
        }
        asm volatile("s_waitcnt vmcnt(0)" ::: "memory");
        __builtin_amdgcn_s_barrier();

        // phase B: compute buf1 (k0+32); prefetch k0+64 -> buf0
        if (k0 + 64 < KTOT) { STG(0, k0 + 64); }
        {
            bf16x8 af[4], bfr[4];
#pragma unroll
            for (int m = 0; m < 4; ++m) af[m]  = *(const bf16x8*)&As[4096 + (wr + m*16 + fr)*32 + g0];
#pragma unroll
            for (int n = 0; n < 4; ++n) bfr[n] = *(const bf16x8*)&Bs[4096 + (wc + n*16 + fr)*32 + g0];
            __builtin_amdgcn_s_setprio(1);
#pragma unroll
            for (int m = 0; m < 4; ++m)
#pragma unroll
                for (int n = 0; n < 4; ++n)
                    acc[m][n] = __builtin_amdgcn_mfma_f32_16x16x32_bf16(af[m], bfr[n], acc[m][n], 0, 0, 0);
            __builtin_amdgcn_s_setprio(0);
        }
        asm volatile("s_waitcnt vmcnt(0)" ::: "memory");
        __builtin_amdgcn_s_barrier();
    }
#undef STG
}

// ---------------- fp32 -> bf16 conversion ----------------
__global__ void cvt_kernel(const float* __restrict__ in, unsigned short* __restrict__ out, int n4) {
    int i = blockIdx.x * blockDim.x + threadIdx.x;
    int stride = gridDim.x * blockDim.x;
    for (; i < n4; i += stride) {
        float4 v = reinterpret_cast<const float4*>(in)[i];
        ushort4 o;
        o.x = f2bf(v.x); o.y = f2bf(v.y); o.z = f2bf(v.z); o.w = f2bf(v.w);
        reinterpret_cast<ushort4*>(out)[i] = o;
    }
}

// ---------------- router (also emits xb bf16) ----------------
__global__ __launch_bounds__(64) void router_kernel(
    const float* __restrict__ x, const float* __restrict__ rw, const float* __restrict__ rb,
    unsigned short* __restrict__ xb,
    int* __restrict__ tidx, float* __restrict__ tgate, int* __restrict__ counts)
{
    int t = blockIdx.x;
    int lane = threadIdx.x;
    const float4* xr4 = reinterpret_cast<const float4*>(x + (size_t)t * DIM);
    ushort4* xb4 = reinterpret_cast<ushort4*>(xb + (size_t)t * DIM);
    float acc[NEXP];
#pragma unroll
    for (int e = 0; e < NEXP; ++e) acc[e] = 0.f;
#pragma unroll
    for (int i = 0; i < 4; ++i) {
        float4 xv = xr4[lane + 64*i];
        ushort4 o;
        o.x = f2bf(xv.x); o.y = f2bf(xv.y); o.z = f2bf(xv.z); o.w = f2bf(xv.w);
        xb4[lane + 64*i] = o;
#pragma unroll
        for (int e = 0; e < NEXP; ++e) {
            float4 wv = reinterpret_cast<const float4*>(rw + e*DIM)[lane + 64*i];
            acc[e] += xv.x*wv.x + xv.y*wv.y + xv.z*wv.z + xv.w*wv.w;
        }
    }
#pragma unroll
    for (int e = 0; e < NEXP; ++e) {
        float v = acc[e];
#pragma unroll
        for (int off = 32; off >= 1; off >>= 1) v += __shfl_xor(v, off);
        acc[e] = v + rb[e];
    }
    int i0 = 0;
#pragma unroll
    for (int e = 1; e < NEXP; ++e) if (acc[e] > acc[i0]) i0 = e;
    int i1 = (i0 == 0) ? 1 : 0;
#pragma unroll
    for (int e = 0; e < NEXP; ++e) if (e != i0 && acc[e] > acc[i1]) i1 = e;

    float mx = acc[i0];
    float den = 0.f;
    float pe[NEXP];
#pragma unroll
    for (int e = 0; e < NEXP; ++e) { pe[e] = __expf(acc[e] - mx); den += pe[e]; }
    float inv = 1.f / den;
    if (lane == 0) {
        tidx[2*t]   = i0;  tidx[2*t+1]  = i1;
        tgate[2*t]  = pe[i0]*inv; tgate[2*t+1] = pe[i1]*inv;
        atomicAdd(&counts[i0], 1);
        atomicAdd(&counts[i1], 1);
    }
}

// ---------------- plan: offsets + XCD-aware worklists ----------------
// Panel = group of items sharing one B-tile (gemm1: (e,nt); gemm2: (e,nt,ks)).
// Panel pid -> XCD pid%8. Worklist slot p is consumed only by blocks with
// blockIdx%8 == p%8 (grid-stride, NBLK%8==0) -> panel stays in ONE XCD's L2.
// Queues padded to equal length with -1 sentinels (bijective mapping).
__global__ void plan_kernel(const int* __restrict__ counts, int* __restrict__ offsets,
                            int* __restrict__ wl1, int* __restrict__ wl2, int* __restrict__ nits)
{
    if (threadIdx.x == 0 && blockIdx.x == 0) {
        int s = 0;
        for (int e = 0; e < NEXP; ++e) { offsets[e] = s; s += counts[e]; }

        int len1[8]; for (int i = 0; i < 8; ++i) len1[i] = 0;
        int pid = 0;
        for (int e = 0; e < NEXP; ++e) {
            int T = (counts[e] + 127) >> 7;
            for (int nt = 0; nt < HID/128; ++nt) {
                int x = (pid++) & 7;
                for (int mt = 0; mt < T; ++mt)
                    wl1[x + 8*(len1[x]++)] = (e << 20) | (mt << 8) | nt;
            }
        }
        int q1 = 0; for (int i = 0; i < 8; ++i) q1 = len1[i] > q1 ? len1[i] : q1;
        for (int x = 0; x < 8; ++x)
            for (int k = len1[x]; k < q1; ++k) wl1[x + 8*k] = -1;

        int len2[8]; for (int i = 0; i < 8; ++i) len2[i] = 0;
        pid = 0;
        for (int e = 0; e < NEXP; ++e) {
            int T = (counts[e] + 127) >> 7;
            for (int nt = 0; nt < DIM/128; ++nt)
                for (int ks = 0; ks < 2; ++ks) {
                    int x = (pid++) & 7;
                    for (int mt = 0; mt < T; ++mt)
                        wl2[x + 8*(len2[x]++)] = (e << 20) | (mt << 8) | (nt << 1) | ks;
                }
        }
        int q2 = 0; for (int i = 0; i < 8; ++i) q2 = len2[i] > q2 ? len2[i] : q2;
        for (int x = 0; x < 8; ++x)
            for (int k = len2[x]; k < q2; ++k) wl2[x + 8*k] = -1;

        nits[0] = 8*q1; nits[1] = 8*q2;
    }
}

__global__ void assign_kernel(const int* __restrict__ tidx, const float* __restrict__ tgate,
                              const int* __restrict__ offsets, int* __restrict__ counts2,
                              int* __restrict__ rowtok, float* __restrict__ rowgate)
{
    int t = blockIdx.x * blockDim.x + threadIdx.x;
    if (t >= N_TOK) return;
#pragma unroll
    for (int k = 0; k < TOPK; ++k) {
        int e = tidx[2*t+k];
        int pos = atomicAdd(&counts2[e], 1);
        int r = offsets[e] + pos;
        rowtok[r]  = t;
        rowgate[r] = tgate[2*t+k];
    }
}

// ---------------- GEMM1 (persistent): hg = gelu(Xg @ w1[e]^T + b1[e]) ----------------
__global__ __launch_bounds__(256, 4) void gemm1_kernel(
    const unsigned short* __restrict__ xb,
    const unsigned short* __restrict__ w1b,
    const float* __restrict__ b1,
    const int* __restrict__ rowtok,
    const int* __restrict__ counts, const int* __restrict__ offsets,
    const int* __restrict__ wl, const int* __restrict__ nits,
    unsigned short* __restrict__ hg)
{
    __shared__ unsigned short As[8192];   // 2 x [128 rows][32 elems]
    __shared__ unsigned short Bs[8192];

    int tid  = threadIdx.x;
    int l    = tid & 63;
    int wid  = tid >> 6;
    int c0 = wid*2, c1 = wid*2 + 1;
    int sr0 = c0*16 + (l >> 2);
    int sr1 = c1*16 + (l >> 2);
    int sgel = (((l & 3) ^ ((l >> 3) & 3)) << 3);   // pre-swizzled source granule
    unsigned short* asD0 = &As[c0*512];
    unsigned short* asD1 = &As[c1*512];
    unsigned short* bsD0 = &Bs[c0*512];
    unsigned short* bsD1 = &Bs[c1*512];

    int fr = l & 15, hi = l >> 4;
    int wr = (wid >> 1) << 6;
    int wc = (wid & 1)  << 6;
    int g0 = ((hi ^ ((fr >> 1) & 3)) << 3);   // swizzled read granule offset

    const int nitems = nits[0];

    for (int it = blockIdx.x; it < nitems; it += NBLK) {
        int wle = wl[it];
        if (wle < 0) continue;                 // padding slot (uniform branch)
        int e = wle >> 20, mt = (wle >> 8) & 0xFFF, nt = wle & 0xFF;
        int cnt  = counts[e];
        int base = offsets[e];
        int nbase = nt * 128;

        int r0 = mt*128 + sr0; if (r0 >= cnt) r0 = cnt - 1;
        int r1 = mt*128 + sr1; if (r1 >= cnt) r1 = cnt - 1;
        int tok0 = rowtok[base + r0];
        int tok1 = rowtok[base + r1];

        const unsigned short* wE  = w1b + (size_t)e * HID * DIM;
        const unsigned short* aG0 = xb + (size_t)tok0 * DIM + sgel;
        const unsigned short* aG1 = xb + (size_t)tok1 * DIM + sgel;
        const unsigned short* bG0 = wE + (size_t)(nbase + sr0) * DIM + sgel;
        const unsigned short* bG1 = wE + (size_t)(nbase + sr1) * DIM + sgel;

        f32x4 acc[4][4];
#pragma unroll
        for (int m = 0; m < 4; ++m)
#pragma unroll
            for (int n = 0; n < 4; ++n)
#pragma unroll
                for (int j = 0; j < 4; ++j) acc[m][n][j] = 0.f;

        kloop<DIM>(aG0, aG1, bG0, bG1, As, Bs, asD0, asD1, bsD0, bsD1, wr, wc, fr, g0, acc);

        const float* b1e = b1 + (size_t)e * HID;
#pragma unroll
        for (int m = 0; m < 4; ++m) {
            int rbase = wr + m*16 + hi*4;
#pragma unroll
            for (int j = 0; j < 4; ++j) {
                int grow = mt*128 + rbase + j;
                if (grow < cnt) {
                    size_t rowoff = (size_t)(base + grow) * HID;
#pragma unroll
                    for (int n = 0; n < 4; ++n) {
                        int col = nbase + wc + n*16 + fr;
                        float v = acc[m][n][j] + b1e[col];
                        float u  = 0.7978845608028654f * (v + 0.044715f * v * v * v);
                        float ex = __expf(2.f * u);
                        float th = 1.f - 2.f / (ex + 1.f);
                        hg[rowoff + col] = f2bf(0.5f * v * (1.f + th));
                    }
                }
            }
        }
        __syncthreads();   // all lanes done with LDS before next item restages
    }
}

// ---------------- GEMM2 (persistent): y[tok] += gate * (hg @ w2[e]^T + b2[e]) ----------------
__global__ __launch_bounds__(256, 4) void gemm2_kernel(
    const unsigned short* __restrict__ hg,
    const unsigned short* __restrict__ w2b,
    const float* __restrict__ b2,
    const int* __restrict__ rowtok, const float* __restrict__ rowgate,
    const int* __restrict__ counts, const int* __restrict__ offsets,
    const int* __restrict__ wl, const int* __restrict__ nits,
    float* __restrict__ y)
{
    __shared__ unsigned short As[8192];
    __shared__ unsigned short Bs[8192];

    int tid  = threadIdx.x;
    int l    = tid & 63;
    int wid  = tid >> 6;
    int c0 = wid*2, c1 = wid*2 + 1;
    int sr0 = c0*16 + (l >> 2);
    int sr1 = c1*16 + (l >> 2);
    int sgel = (((l & 3) ^ ((l >> 3) & 3)) << 3);
    unsigned short* asD0 = &As[c0*512];
    unsigned short* asD1 = &As[c1*512];
    unsigned short* bsD0 = &Bs[c0*512];
    unsigned short* bsD1 = &Bs[c1*512];

    int fr = l & 15, hi = l >> 4;
    int wr = (wid >> 1) << 6;
    int wc = (wid & 1)  << 6;
    int g0 = ((hi ^ ((fr >> 1) & 3)) << 3);

    const int nitems = nits[1];

    for (int it = blockIdx.x; it < nitems; it += NBLK) {
        int wle = wl[it];
        if (wle < 0) continue;                 // padding slot
        int e = wle >> 20, mt = (wle >> 8) & 0xFFF;
        int nt = (wle & 0xFF) >> 1, ks = wle & 1;
        int cnt  = counts[e];
        int base = offsets[e];
        int nbase = nt * 128;
        int kofs  = ks * (HID/2);

        int r0 = mt*128 + sr0; if (r0 >= cnt) r0 = cnt - 1;
        int r1 = mt*128 + sr1; if (r1 >= cnt) r1 = cnt - 1;

        const unsigned short* wE  = w2b + (size_t)e * DIM * HID + kofs;
        const unsigned short* aG0 = hg + (size_t)(base + r0) * HID + kofs + sgel;
        const unsigned short* aG1 = hg + (size_t)(base + r1) * HID + kofs + sgel;
        const unsigned short* bG0 = wE + (size_t)(nbase + sr0) * HID + sgel;
        const unsigned short* bG1 = wE + (size_t)(nbase + sr1) * HID + sgel;

        f32x4 acc[4][4];
#pragma unroll
        for (int m = 0; m < 4; ++m)
#pragma unroll
            for (int n = 0; n < 4; ++n)
#pragma unroll
                for (int j = 0; j < 4; ++j) acc[m][n][j] = 0.f;

        kloop<HID/2>(aG0, aG1, bG0, bG1, As, Bs, asD0, asD1, bsD0, bsD1, wr, wc, fr, g0, acc);

        const float* b2e = b2 + (size_t)e * DIM;
#pragma unroll
        for (int m = 0; m < 4; ++m) {
            int rbase = wr + m*16 + hi*4;
#pragma unroll
            for (int j = 0; j < 4; ++j) {
                int grow = mt*128 + rbase + j;
                if (grow < cnt) {
                    int tok = rowtok[base + grow];
                    float g = rowgate[base + grow];
#pragma unroll
                    for (int n = 0; n < 4; ++n) {
                        int col = nbase + wc + n*16 + fr;
                        float v = acc[m][n][j] + (ks == 0 ? b2e[col] : 0.f);
                        atomicAdd(&y[(size_t)tok * DIM + col], g * v);
                    }
                }
            }
        }
        __syncthreads();
    }
}

// ---------------- workspace layout ----------------
static constexpr size_t XB_OFF   = 0;
static constexpr size_t W1B_OFF  = XB_OFF  + (size_t)N_TOK * DIM * 2;
static constexpr size_t W2B_OFF  = W1B_OFF + (size_t)NEXP * HID * DIM * 2;
static constexpr size_t HG_OFF   = W2B_OFF + (size_t)NEXP * DIM * HID * 2;
static constexpr size_t RT_OFF   = HG_OFF  + (size_t)M_TOT * HID * 2;
static constexpr size_t RG_OFF   = RT_OFF  + (size_t)M_TOT * 4;
static constexpr size_t TI_OFF   = RG_OFF  + (size_t)M_TOT * 4;
static constexpr size_t TG_OFF   = TI_OFF  + (size_t)N_TOK * TOPK * 4;
static constexpr size_t META_OFF = TG_OFF  + (size_t)N_TOK * TOPK * 4;
static constexpr size_t WL1_OFF  = META_OFF + 256;
static constexpr size_t WL2_OFF  = WL1_OFF + 8192 * 4;
static constexpr size_t WS_NEED  = WL2_OFF + 4096 * 4;

extern "C" void kernel_launch(void* const* d_in, const int* in_sizes, int n_in,
                              void* d_out, int out_size, void* d_ws, size_t ws_size,
                              hipStream_t stream)
{
    if (ws_size < WS_NEED) return;

    const float* x  = (const float*)d_in[0];
    const float* rw = (const float*)d_in[1];
    const float* rb = (const float*)d_in[2];
    const float* w1 = (const float*)d_in[3];
    const float* b1 = (const float*)d_in[4];
    const float* w2 = (const float*)d_in[5];
    const float* b2 = (const float*)d_in[6];
    float* y = (float*)d_out;

    char* ws = (char*)d_ws;
    unsigned short* xb  = (unsigned short*)(ws + XB_OFF);
    unsigned short* w1b = (unsigned short*)(ws + W1B_OFF);
    unsigned short* w2b = (unsigned short*)(ws + W2B_OFF);
    unsigned short* hg  = (unsigned short*)(ws + HG_OFF);
    int*   rowtok  = (int*)  (ws + RT_OFF);
    float* rowgate = (float*)(ws + RG_OFF);
    int*   tidx    = (int*)  (ws + TI_OFF);
    float* tgate   = (float*)(ws + TG_OFF);
    int*   meta    = (int*)  (ws + META_OFF);
    int*   wl1     = (int*)  (ws + WL1_OFF);
    int*   wl2     = (int*)  (ws + WL2_OFF);
    int* counts  = meta;         // [0..7]
    int* counts2 = meta + 8;     // [8..15]
    int* offsets = meta + 16;    // [16..23]
    int* nits    = meta + 26;    // [26..27]

    hipMemsetAsync(meta, 0, 128, stream);
    hipMemsetAsync(y, 0, (size_t)out_size * 4, stream);

    cvt_kernel<<<2048, 256, 0, stream>>>(w1, w1b, NEXP*HID*DIM/4);
    cvt_kernel<<<2048, 256, 0, stream>>>(w2, w2b, NEXP*DIM*HID/4);

    router_kernel<<<N_TOK, 64, 0, stream>>>(x, rw, rb, xb, tidx, tgate, counts);
    plan_kernel<<<1, 64, 0, stream>>>(counts, offsets, wl1, wl2, nits);
    assign_kernel<<<N_TOK/256, 256, 0, stream>>>(tidx, tgate, offsets, counts2, rowtok, rowgate);

    gemm1_kernel<<<NBLK, 256, 0, stream>>>(xb, w1b, b1, rowtok, counts, offsets, wl1, nits, hg);
    gemm2_kernel<<<NBLK, 256, 0, stream>>>(hg, w2b, b2, rowtok, rowgate, counts, offsets, wl2, nits, y);
}

// Round 13
// 891.582 us; speedup vs baseline: 1.5876x; 1.5876x over previous
//
#include <hip/hip_runtime.h>
#include <hip/hip_bf16.h>

#define N_TOK 8192
#define DIM   1024
#define HID   4096
#define NEXP  8
#define TOPK  2
#define M_TOT (N_TOK*TOPK)

typedef __bf16 bf16x8 __attribute__((ext_vector_type(8)));
typedef float  f32x4  __attribute__((ext_vector_type(4)));

__device__ __forceinline__ unsigned short f2bf(float f) {
    union { __hip_bfloat16 h; unsigned short u; } c;
    c.h = __float2bfloat16(f);
    return c.u;
}

// async global->LDS, 16B/lane. LDS dest wave-uniform base; lane l -> base + l*16B.
__device__ __forceinline__ void gload16(const unsigned short* g, unsigned short* l) {
    __builtin_amdgcn_global_load_lds(
        (const __attribute__((address_space(1))) void*)g,
        (__attribute__((address_space(3))) void*)l,
        16, 0, 0);
}

// ---------------------------------------------------------------------------
// 128x128 tile, BK=32, 4 waves (each 64x64 = 4x4 frags of 16x16x32 MFMA).
// Double-buffered LDS (2 x 8KB per operand), stage-early 2-phase.
// LDS granule swizzle (verified on-HW in R8/R9: SQ_LDS_BANK_CONFLICT=0,
// output correct): LDS[row][s] holds logical granule s ^ ((row>>1)&3);
// staged via pre-swizzled GLOBAL source offset (gload_lds dest stays
// linear), read at slot hi ^ ((fr>>1)&3).
// ---------------------------------------------------------------------------
template<int KTOT>
__device__ __forceinline__ void kloop(
    const unsigned short* __restrict__ aG0, const unsigned short* __restrict__ aG1,
    const unsigned short* __restrict__ bG0, const unsigned short* __restrict__ bG1,
    unsigned short* As, unsigned short* Bs,
    unsigned short* asD0, unsigned short* asD1,
    unsigned short* bsD0, unsigned short* bsD1,
    int wr, int wc, int fr, int g0,
    f32x4 (&acc)[4][4])
{
#define STG(B, K) \
    gload16(aG0 + (K), asD0 + (B)*4096); \
    gload16(aG1 + (K), asD1 + (B)*4096); \
    gload16(bG0 + (K), bsD0 + (B)*4096); \
    gload16(bG1 + (K), bsD1 + (B)*4096)

    STG(0, 0);
    asm volatile("s_waitcnt vmcnt(0)" ::: "memory");
    __builtin_amdgcn_s_barrier();

#pragma unroll 1
    for (int k0 = 0; k0 < KTOT; k0 += 64) {
        // phase A: compute buf0 (k0); prefetch k0+32 -> buf1
        STG(1, k0 + 32);
        {
            bf16x8 af[4], bfr[4];
#pragma unroll
            for (int m = 0; m < 4; ++m) af[m]  = *(const bf16x8*)&As[(wr + m*16 + fr)*32 + g0];
#pragma unroll
            for (int n = 0; n < 4; ++n) bfr[n] = *(const bf16x8*)&Bs[(wc + n*16 + fr)*32 + g0];
            __builtin_amdgcn_s_setprio(1);
#pragma unroll
            for (int m = 0; m < 4; ++m)
#pragma unroll
                for (int n = 0; n < 4; ++n)
                    acc[m][n] = __builtin_amdgcn_mfma_f32_16x16x32_bf16(af[m], bfr[n], acc[m][n], 0, 0, 0);
            __builtin_amdgcn_s_setprio(0);
        }
        asm volatile("s_waitcnt vmcnt(0)" ::: "memory");
        __builtin_amdgcn_s_barrier();

        // phase B: compute buf1 (k0+32); prefetch k0+64 -> buf0
        if (k0 + 64 < KTOT) { STG(0, k0 + 64); }
        {
            bf16x8 af[4], bfr[4];
#pragma unroll
            for (int m = 0; m < 4; ++m) af[m]  = *(const bf16x8*)&As[4096 + (wr + m*16 + fr)*32 + g0];
#pragma unroll
            for (int n = 0; n < 4; ++n) bfr[n] = *(const bf16x8*)&Bs[4096 + (wc + n*16 + fr)*32 + g0];
            __builtin_amdgcn_s_setprio(1);
#pragma unroll
            for (int m = 0; m < 4; ++m)
#pragma unroll
                for (int n = 0; n < 4; ++n)
                    acc[m][n] = __builtin_amdgcn_mfma_f32_16x16x32_bf16(af[m], bfr[n], acc[m][n], 0, 0, 0);
            __builtin_amdgcn_s_setprio(0);
        }
        asm volatile("s_waitcnt vmcnt(0)" ::: "memory");
        __builtin_amdgcn_s_barrier();
    }
#undef STG
}

// ---------------- fp32 -> bf16 conversion ----------------
__global__ void cvt_kernel(const float* __restrict__ in, unsigned short* __restrict__ out, int n4) {
    int i = blockIdx.x * blockDim.x + threadIdx.x;
    int stride = gridDim.x * blockDim.x;
    for (; i < n4; i += stride) {
        float4 v = reinterpret_cast<const float4*>(in)[i];
        ushort4 o;
        o.x = f2bf(v.x); o.y = f2bf(v.y); o.z = f2bf(v.z); o.w = f2bf(v.w);
        reinterpret_cast<ushort4*>(out)[i] = o;
    }
}

// ---------------- router (also emits xb bf16) ----------------
__global__ __launch_bounds__(64) void router_kernel(
    const float* __restrict__ x, const float* __restrict__ rw, const float* __restrict__ rb,
    unsigned short* __restrict__ xb,
    int* __restrict__ tidx, float* __restrict__ tgate, int* __restrict__ counts)
{
    int t = blockIdx.x;
    int lane = threadIdx.x;
    const float4* xr4 = reinterpret_cast<const float4*>(x + (size_t)t * DIM);
    ushort4* xb4 = reinterpret_cast<ushort4*>(xb + (size_t)t * DIM);
    float acc[NEXP];
#pragma unroll
    for (int e = 0; e < NEXP; ++e) acc[e] = 0.f;
#pragma unroll
    for (int i = 0; i < 4; ++i) {
        float4 xv = xr4[lane + 64*i];
        ushort4 o;
        o.x = f2bf(xv.x); o.y = f2bf(xv.y); o.z = f2bf(xv.z); o.w = f2bf(xv.w);
        xb4[lane + 64*i] = o;
#pragma unroll
        for (int e = 0; e < NEXP; ++e) {
            float4 wv = reinterpret_cast<const float4*>(rw + e*DIM)[lane + 64*i];
            acc[e] += xv.x*wv.x + xv.y*wv.y + xv.z*wv.z + xv.w*wv.w;
        }
    }
#pragma unroll
    for (int e = 0; e < NEXP; ++e) {
        float v = acc[e];
#pragma unroll
        for (int off = 32; off >= 1; off >>= 1) v += __shfl_xor(v, off);
        acc[e] = v + rb[e];
    }
    int i0 = 0;
#pragma unroll
    for (int e = 1; e < NEXP; ++e) if (acc[e] > acc[i0]) i0 = e;
    int i1 = (i0 == 0) ? 1 : 0;
#pragma unroll
    for (int e = 0; e < NEXP; ++e) if (e != i0 && acc[e] > acc[i1]) i1 = e;

    float mx = acc[i0];
    float den = 0.f;
    float pe[NEXP];
#pragma unroll
    for (int e = 0; e < NEXP; ++e) { pe[e] = __expf(acc[e] - mx); den += pe[e]; }
    float inv = 1.f / den;
    if (lane == 0) {
        tidx[2*t]   = i0;  tidx[2*t+1]  = i1;
        tgate[2*t]  = pe[i0]*inv; tgate[2*t+1] = pe[i1]*inv;
        atomicAdd(&counts[i0], 1);
        atomicAdd(&counts[i1], 1);
    }
}

__global__ void prefix_kernel(const int* __restrict__ counts, int* __restrict__ offsets) {
    if (threadIdx.x == 0 && blockIdx.x == 0) {
        int s = 0;
        for (int e = 0; e < NEXP; ++e) { offsets[e] = s; s += counts[e]; }
    }
}

__global__ void assign_kernel(const int* __restrict__ tidx, const float* __restrict__ tgate,
                              const int* __restrict__ offsets, int* __restrict__ counts2,
                              int* __restrict__ rowtok, float* __restrict__ rowgate)
{
    int t = blockIdx.x * blockDim.x + threadIdx.x;
    if (t >= N_TOK) return;
#pragma unroll
    for (int k = 0; k < TOPK; ++k) {
        int e = tidx[2*t+k];
        int pos = atomicAdd(&counts2[e], 1);
        int r = offsets[e] + pos;
        rowtok[r]  = t;
        rowgate[r] = tgate[2*t+k];
    }
}

// ---------------- GEMM1: hg = gelu(Xg @ w1[e]^T + b1[e]) ----------------
__global__ __launch_bounds__(256) void gemm1_kernel(
    const unsigned short* __restrict__ xb,      // N x D bf16
    const unsigned short* __restrict__ w1b,     // E x H x D bf16
    const float* __restrict__ b1,               // E x H
    const int* __restrict__ rowtok,
    const int* __restrict__ counts, const int* __restrict__ offsets,
    unsigned short* __restrict__ hg)            // M_TOT x H bf16
{
    int e   = blockIdx.z;
    int cnt = counts[e];
    int mt  = blockIdx.y;
    if (mt * 128 >= cnt) return;
    int base  = offsets[e];
    int nbase = blockIdx.x * 128;

    __shared__ unsigned short As[8192];   // 2 x [128][32]
    __shared__ unsigned short Bs[8192];
    __shared__ int rowids[128];

    int tid = threadIdx.x;
    if (tid < 128) {
        int r = mt*128 + tid;
        rowids[tid] = rowtok[base + (r < cnt ? r : cnt - 1)];
    }
    __syncthreads();

    int lane = tid & 63;
    int wid  = tid >> 6;
    int c0 = wid*2, c1 = wid*2 + 1;
    int sr0 = c0*16 + (lane >> 2);
    int sr1 = c1*16 + (lane >> 2);
    int sgel = (((lane & 3) ^ ((lane >> 3) & 3)) << 3);   // pre-swizzled source granule

    const unsigned short* wE  = w1b + (size_t)e * HID * DIM;
    const unsigned short* aG0 = xb + (size_t)rowids[sr0] * DIM + sgel;
    const unsigned short* aG1 = xb + (size_t)rowids[sr1] * DIM + sgel;
    const unsigned short* bG0 = wE + (size_t)(nbase + sr0) * DIM + sgel;
    const unsigned short* bG1 = wE + (size_t)(nbase + sr1) * DIM + sgel;
    unsigned short* asD0 = &As[c0*512];
    unsigned short* asD1 = &As[c1*512];
    unsigned short* bsD0 = &Bs[c0*512];
    unsigned short* bsD1 = &Bs[c1*512];

    int wr = (wid >> 1) << 6;
    int wc = (wid & 1)  << 6;
    int fr = lane & 15;
    int hi = lane >> 4;
    int g0 = ((hi ^ ((fr >> 1) & 3)) << 3);   // swizzled read granule offset

    f32x4 acc[4][4];
#pragma unroll
    for (int m = 0; m < 4; ++m)
#pragma unroll
        for (int n = 0; n < 4; ++n)
#pragma unroll
            for (int j = 0; j < 4; ++j) acc[m][n][j] = 0.f;

    kloop<DIM>(aG0, aG1, bG0, bG1, As, Bs, asD0, asD1, bsD0, bsD1, wr, wc, fr, g0, acc);

    const float* b1e = b1 + (size_t)e * HID;
#pragma unroll
    for (int m = 0; m < 4; ++m) {
        int rbase = wr + m*16 + hi*4;
#pragma unroll
        for (int j = 0; j < 4; ++j) {
            int grow = mt*128 + rbase + j;
            if (grow < cnt) {
                size_t rowoff = (size_t)(base + grow) * HID;
#pragma unroll
                for (int n = 0; n < 4; ++n) {
                    int col = nbase + wc + n*16 + fr;
                    float v = acc[m][n][j] + b1e[col];
                    float u  = 0.7978845608028654f * (v + 0.044715f * v * v * v);
                    float ex = __expf(2.f * u);
                    float th = 1.f - 2.f / (ex + 1.f);
                    hg[rowoff + col] = f2bf(0.5f * v * (1.f + th));
                }
            }
        }
    }
}

// ---------------- GEMM2: y[tok] += gate * (hg @ w2[e]^T + b2[e]) ----------------
// blockIdx.z = e*2 + ks; each computes a K-half (2048), atomically merged.
__global__ __launch_bounds__(256) void gemm2_kernel(
    const unsigned short* __restrict__ hg,      // M_TOT x H bf16
    const unsigned short* __restrict__ w2b,     // E x D x H bf16
    const float* __restrict__ b2,               // E x D
    const int* __restrict__ rowtok, const float* __restrict__ rowgate,
    const int* __restrict__ counts, const int* __restrict__ offsets,
    float* __restrict__ y)                      // N x D fp32 (pre-zeroed)
{
    int e   = blockIdx.z >> 1;
    int ks  = blockIdx.z & 1;
    int cnt = counts[e];
    int mt  = blockIdx.y;
    if (mt * 128 >= cnt) return;
    int base  = offsets[e];
    int nbase = blockIdx.x * 128;
    int kofs  = ks * (HID/2);

    __shared__ unsigned short As[8192];
    __shared__ unsigned short Bs[8192];

    int tid  = threadIdx.x;
    int lane = tid & 63;
    int wid  = tid >> 6;
    int c0 = wid*2, c1 = wid*2 + 1;
    int sr0 = c0*16 + (lane >> 2);
    int sr1 = c1*16 + (lane >> 2);
    int sgel = (((lane & 3) ^ ((lane >> 3) & 3)) << 3);

    int ar0 = mt*128 + sr0; if (ar0 >= cnt) ar0 = cnt - 1;
    int ar1 = mt*128 + sr1; if (ar1 >= cnt) ar1 = cnt - 1;
    const unsigned short* wE  = w2b + (size_t)e * DIM * HID + kofs;
    const unsigned short* aG0 = hg + (size_t)(base + ar0) * HID + kofs + sgel;
    const unsigned short* aG1 = hg + (size_t)(base + ar1) * HID + kofs + sgel;
    const unsigned short* bG0 = wE + (size_t)(nbase + sr0) * HID + sgel;
    const unsigned short* bG1 = wE + (size_t)(nbase + sr1) * HID + sgel;
    unsigned short* asD0 = &As[c0*512];
    unsigned short* asD1 = &As[c1*512];
    unsigned short* bsD0 = &Bs[c0*512];
    unsigned short* bsD1 = &Bs[c1*512];

    int wr = (wid >> 1) << 6;
    int wc = (wid & 1)  << 6;
    int fr = lane & 15;
    int hi = lane >> 4;
    int g0 = ((hi ^ ((fr >> 1) & 3)) << 3);

    f32x4 acc[4][4];
#pragma unroll
    for (int m = 0; m < 4; ++m)
#pragma unroll
        for (int n = 0; n < 4; ++n)
#pragma unroll
            for (int j = 0; j < 4; ++j) acc[m][n][j] = 0.f;

    kloop<HID/2>(aG0, aG1, bG0, bG1, As, Bs, asD0, asD1, bsD0, bsD1, wr, wc, fr, g0, acc);

    const float* b2e = b2 + (size_t)e * DIM;
#pragma unroll
    for (int m = 0; m < 4; ++m) {
        int rbase = wr + m*16 + hi*4;
#pragma unroll
        for (int j = 0; j < 4; ++j) {
            int grow = mt*128 + rbase + j;
            if (grow < cnt) {
                int tok = rowtok[base + grow];
                float g = rowgate[base + grow];
#pragma unroll
                for (int n = 0; n < 4; ++n) {
                    int col = nbase + wc + n*16 + fr;
                    float v = acc[m][n][j] + (ks == 0 ? b2e[col] : 0.f);
                    atomicAdd(&y[(size_t)tok * DIM + col], g * v);
                }
            }
        }
    }
}

// ---------------- workspace layout ----------------
static constexpr size_t XB_OFF   = 0;
static constexpr size_t W1B_OFF  = XB_OFF  + (size_t)N_TOK * DIM * 2;
static constexpr size_t W2B_OFF  = W1B_OFF + (size_t)NEXP * HID * DIM * 2;
static constexpr size_t HG_OFF   = W2B_OFF + (size_t)NEXP * DIM * HID * 2;
static constexpr size_t RT_OFF   = HG_OFF  + (size_t)M_TOT * HID * 2;
static constexpr size_t RG_OFF   = RT_OFF  + (size_t)M_TOT * 4;
static constexpr size_t TI_OFF   = RG_OFF  + (size_t)M_TOT * 4;
static constexpr size_t TG_OFF   = TI_OFF  + (size_t)N_TOK * TOPK * 4;
static constexpr size_t META_OFF = TG_OFF  + (size_t)N_TOK * TOPK * 4;
static constexpr size_t WS_NEED  = META_OFF + 256;

extern "C" void kernel_launch(void* const* d_in, const int* in_sizes, int n_in,
                              void* d_out, int out_size, void* d_ws, size_t ws_size,
                              hipStream_t stream)
{
    if (ws_size < WS_NEED) return;

    const float* x  = (const float*)d_in[0];
    const float* rw = (const float*)d_in[1];
    const float* rb = (const float*)d_in[2];
    const float* w1 = (const float*)d_in[3];
    const float* b1 = (const float*)d_in[4];
    const float* w2 = (const float*)d_in[5];
    const float* b2 = (const float*)d_in[6];
    float* y = (float*)d_out;

    char* ws = (char*)d_ws;
    unsigned short* xb  = (unsigned short*)(ws + XB_OFF);
    unsigned short* w1b = (unsigned short*)(ws + W1B_OFF);
    unsigned short* w2b = (unsigned short*)(ws + W2B_OFF);
    unsigned short* hg  = (unsigned short*)(ws + HG_OFF);
    int*   rowtok  = (int*)  (ws + RT_OFF);
    float* rowgate = (float*)(ws + RG_OFF);
    int*   tidx    = (int*)  (ws + TI_OFF);
    float* tgate   = (float*)(ws + TG_OFF);
    int*   meta    = (int*)  (ws + META_OFF);
    int* counts  = meta;        // 8 ints
    int* counts2 = meta + 8;    // 8 ints
    int* offsets = meta + 16;   // 8 ints

    hipMemsetAsync(meta, 0, 64, stream);
    hipMemsetAsync(y, 0, (size_t)out_size * 4, stream);

    cvt_kernel<<<2048, 256, 0, stream>>>(w1, w1b, NEXP*HID*DIM/4);
    cvt_kernel<<<2048, 256, 0, stream>>>(w2, w2b, NEXP*DIM*HID/4);

    router_kernel<<<N_TOK, 64, 0, stream>>>(x, rw, rb, xb, tidx, tgate, counts);
    prefix_kernel<<<1, 64, 0, stream>>>(counts, offsets);
    assign_kernel<<<N_TOK/256, 256, 0, stream>>>(tidx, tgate, offsets, counts2, rowtok, rowgate);

    gemm1_kernel<<<dim3(HID/128, 64, NEXP), 256, 0, stream>>>(xb, w1b, b1, rowtok, counts, offsets, hg);
    gemm2_kernel<<<dim3(DIM/128, 64, NEXP*2), 256, 0, stream>>>(hg, w2b, b2, rowtok, rowgate, counts, offsets, y);
}

// Round 14
// 887.458 us; speedup vs baseline: 1.5949x; 1.0046x over previous
//
#include <hip/hip_runtime.h>
#include <hip/hip_bf16.h>

#define N_TOK 8192
#define DIM   1024
#define HID   4096
#define NEXP  8
#define TOPK  2
#define M_TOT (N_TOK*TOPK)

typedef __bf16 bf16x8 __attribute__((ext_vector_type(8)));
typedef float  f32x4  __attribute__((ext_vector_type(4)));

__device__ __forceinline__ unsigned short f2bf(float f) {
    union { __hip_bfloat16 h; unsigned short u; } c;
    c.h = __float2bfloat16(f);
    return c.u;
}

// async global->LDS, 16B/lane. LDS dest wave-uniform base; lane l -> base + l*16B.
__device__ __forceinline__ void gload16(const unsigned short* g, unsigned short* l) {
    __builtin_amdgcn_global_load_lds(
        (const __attribute__((address_space(1))) void*)g,
        (__attribute__((address_space(3))) void*)l,
        16, 0, 0);
}

// ---------------------------------------------------------------------------
// 128x128 tile, BK=32, 4 waves (each 64x64 = 4x4 frags of 16x16x32 MFMA).
// 3-buffer LDS ring (3 x 8KB per operand = 48KB), COUNTED vmcnt(4):
//   iter j: vmcnt(4) retires exactly tile j (tile j+1 stays in flight);
//   barrier; stage tile j+2 into the slot freed by compute j-1; compute j.
// Stage->gate distance = 2 iterations (~800cy) >= HBM latency; barrier count
// unchanged vs 2-phase (1 per 32-K). Last iteration peeled with vmcnt(0).
// WAR safe: stage slot's readers all passed the barrier (ds_reads retired
// before their MFMA use, which precedes the barrier). VMEM retires in-order.
// LDS granule swizzle (HW-verified R8/R9/R13: SQ_LDS_BANK_CONFLICT=0):
// LDS[row][s] holds granule s ^ ((row>>1)&3); pre-swizzled global source,
// read at slot hi ^ ((fr>>1)&3).
// ---------------------------------------------------------------------------
template<int KTOT>
__device__ __forceinline__ void kloop(
    const unsigned short* __restrict__ aG0, const unsigned short* __restrict__ aG1,
    const unsigned short* __restrict__ bG0, const unsigned short* __restrict__ bG1,
    unsigned short* As, unsigned short* Bs,
    unsigned short* asD0, unsigned short* asD1,
    unsigned short* bsD0, unsigned short* bsD1,
    int wr, int wc, int fr, int g0,
    f32x4 (&acc)[4][4])
{
    constexpr int NT = KTOT / 32;

#define STG(OFS, K) \
    gload16(aG0 + (K), asD0 + (OFS)); \
    gload16(aG1 + (K), asD1 + (OFS)); \
    gload16(bG0 + (K), bsD0 + (OFS)); \
    gload16(bG1 + (K), bsD1 + (OFS))

#define COMPUTE(OFS) { \
    bf16x8 af[4], bfr[4]; \
    _Pragma("unroll") \
    for (int m = 0; m < 4; ++m) af[m]  = *(const bf16x8*)&As[(OFS) + (wr + m*16 + fr)*32 + g0]; \
    _Pragma("unroll") \
    for (int n = 0; n < 4; ++n) bfr[n] = *(const bf16x8*)&Bs[(OFS) + (wc + n*16 + fr)*32 + g0]; \
    __builtin_amdgcn_s_setprio(1); \
    _Pragma("unroll") \
    for (int m = 0; m < 4; ++m) \
        _Pragma("unroll") \
        for (int n = 0; n < 4; ++n) \
            acc[m][n] = __builtin_amdgcn_mfma_f32_16x16x32_bf16(af[m], bfr[n], acc[m][n], 0, 0, 0); \
    __builtin_amdgcn_s_setprio(0); }

    // prologue: tiles 0,1 into slots 0,1
    STG(0, 0);
    STG(4096, 32);

    int cur = 0, nxt = 4096, stg = 8192;
#pragma unroll 1
    for (int j = 0; j < NT - 1; ++j) {
        asm volatile("s_waitcnt vmcnt(4)" ::: "memory");   // tile j resident
        __builtin_amdgcn_s_barrier();
        if (j + 2 < NT) { STG(stg, (j + 2) * 32); }
        COMPUTE(cur)
        int t = cur; cur = nxt; nxt = stg; stg = t;
    }
    asm volatile("s_waitcnt vmcnt(0)" ::: "memory");        // last tile resident
    __builtin_amdgcn_s_barrier();
    COMPUTE(cur)

#undef COMPUTE
#undef STG
}

// ---------------- fp32 -> bf16 conversion ----------------
__global__ void cvt_kernel(const float* __restrict__ in, unsigned short* __restrict__ out, int n4) {
    int i = blockIdx.x * blockDim.x + threadIdx.x;
    int stride = gridDim.x * blockDim.x;
    for (; i < n4; i += stride) {
        float4 v = reinterpret_cast<const float4*>(in)[i];
        ushort4 o;
        o.x = f2bf(v.x); o.y = f2bf(v.y); o.z = f2bf(v.z); o.w = f2bf(v.w);
        reinterpret_cast<ushort4*>(out)[i] = o;
    }
}

// ---------------- router (also emits xb bf16) ----------------
__global__ __launch_bounds__(64) void router_kernel(
    const float* __restrict__ x, const float* __restrict__ rw, const float* __restrict__ rb,
    unsigned short* __restrict__ xb,
    int* __restrict__ tidx, float* __restrict__ tgate, int* __restrict__ counts)
{
    int t = blockIdx.x;
    int lane = threadIdx.x;
    const float4* xr4 = reinterpret_cast<const float4*>(x + (size_t)t * DIM);
    ushort4* xb4 = reinterpret_cast<ushort4*>(xb + (size_t)t * DIM);
    float acc[NEXP];
#pragma unroll
    for (int e = 0; e < NEXP; ++e) acc[e] = 0.f;
#pragma unroll
    for (int i = 0; i < 4; ++i) {
        float4 xv = xr4[lane + 64*i];
        ushort4 o;
        o.x = f2bf(xv.x); o.y = f2bf(xv.y); o.z = f2bf(xv.z); o.w = f2bf(xv.w);
        xb4[lane + 64*i] = o;
#pragma unroll
        for (int e = 0; e < NEXP; ++e) {
            float4 wv = reinterpret_cast<const float4*>(rw + e*DIM)[lane + 64*i];
            acc[e] += xv.x*wv.x + xv.y*wv.y + xv.z*wv.z + xv.w*wv.w;
        }
    }
#pragma unroll
    for (int e = 0; e < NEXP; ++e) {
        float v = acc[e];
#pragma unroll
        for (int off = 32; off >= 1; off >>= 1) v += __shfl_xor(v, off);
        acc[e] = v + rb[e];
    }
    int i0 = 0;
#pragma unroll
    for (int e = 1; e < NEXP; ++e) if (acc[e] > acc[i0]) i0 = e;
    int i1 = (i0 == 0) ? 1 : 0;
#pragma unroll
    for (int e = 0; e < NEXP; ++e) if (e != i0 && acc[e] > acc[i1]) i1 = e;

    float mx = acc[i0];
    float den = 0.f;
    float pe[NEXP];
#pragma unroll
    for (int e = 0; e < NEXP; ++e) { pe[e] = __expf(acc[e] - mx); den += pe[e]; }
    float inv = 1.f / den;
    if (lane == 0) {
        tidx[2*t]   = i0;  tidx[2*t+1]  = i1;
        tgate[2*t]  = pe[i0]*inv; tgate[2*t+1] = pe[i1]*inv;
        atomicAdd(&counts[i0], 1);
        atomicAdd(&counts[i1], 1);
    }
}

__global__ void prefix_kernel(const int* __restrict__ counts, int* __restrict__ offsets) {
    if (threadIdx.x == 0 && blockIdx.x == 0) {
        int s = 0;
        for (int e = 0; e < NEXP; ++e) { offsets[e] = s; s += counts[e]; }
    }
}

__global__ void assign_kernel(const int* __restrict__ tidx, const float* __restrict__ tgate,
                              const int* __restrict__ offsets, int* __restrict__ counts2,
                              int* __restrict__ rowtok, float* __restrict__ rowgate)
{
    int t = blockIdx.x * blockDim.x + threadIdx.x;
    if (t >= N_TOK) return;
#pragma unroll
    for (int k = 0; k < TOPK; ++k) {
        int e = tidx[2*t+k];
        int pos = atomicAdd(&counts2[e], 1);
        int r = offsets[e] + pos;
        rowtok[r]  = t;
        rowgate[r] = tgate[2*t+k];
    }
}

// ---------------- GEMM1: hg = gelu(Xg @ w1[e]^T + b1[e]) ----------------
__global__ __launch_bounds__(256) void gemm1_kernel(
    const unsigned short* __restrict__ xb,      // N x D bf16
    const unsigned short* __restrict__ w1b,     // E x H x D bf16
    const float* __restrict__ b1,               // E x H
    const int* __restrict__ rowtok,
    const int* __restrict__ counts, const int* __restrict__ offsets,
    unsigned short* __restrict__ hg)            // M_TOT x H bf16
{
    int e   = blockIdx.z;
    int cnt = counts[e];
    int mt  = blockIdx.y;
    if (mt * 128 >= cnt) return;
    int base  = offsets[e];
    int nbase = blockIdx.x * 128;

    __shared__ unsigned short As[12288];   // 3 x [128][32]
    __shared__ unsigned short Bs[12288];
    __shared__ int rowids[128];

    int tid = threadIdx.x;
    if (tid < 128) {
        int r = mt*128 + tid;
        rowids[tid] = rowtok[base + (r < cnt ? r : cnt - 1)];
    }
    __syncthreads();

    int lane = tid & 63;
    int wid  = tid >> 6;
    int c0 = wid*2, c1 = wid*2 + 1;
    int sr0 = c0*16 + (lane >> 2);
    int sr1 = c1*16 + (lane >> 2);
    int sgel = (((lane & 3) ^ ((lane >> 3) & 3)) << 3);   // pre-swizzled source granule

    const unsigned short* wE  = w1b + (size_t)e * HID * DIM;
    const unsigned short* aG0 = xb + (size_t)rowids[sr0] * DIM + sgel;
    const unsigned short* aG1 = xb + (size_t)rowids[sr1] * DIM + sgel;
    const unsigned short* bG0 = wE + (size_t)(nbase + sr0) * DIM + sgel;
    const unsigned short* bG1 = wE + (size_t)(nbase + sr1) * DIM + sgel;
    unsigned short* asD0 = &As[c0*512];
    unsigned short* asD1 = &As[c1*512];
    unsigned short* bsD0 = &Bs[c0*512];
    unsigned short* bsD1 = &Bs[c1*512];

    int wr = (wid >> 1) << 6;
    int wc = (wid & 1)  << 6;
    int fr = lane & 15;
    int hi = lane >> 4;
    int g0 = ((hi ^ ((fr >> 1) & 3)) << 3);   // swizzled read granule offset

    f32x4 acc[4][4];
#pragma unroll
    for (int m = 0; m < 4; ++m)
#pragma unroll
        for (int n = 0; n < 4; ++n)
#pragma unroll
            for (int j = 0; j < 4; ++j) acc[m][n][j] = 0.f;

    kloop<DIM>(aG0, aG1, bG0, bG1, As, Bs, asD0, asD1, bsD0, bsD1, wr, wc, fr, g0, acc);

    const float* b1e = b1 + (size_t)e * HID;
#pragma unroll
    for (int m = 0; m < 4; ++m) {
        int rbase = wr + m*16 + hi*4;
#pragma unroll
        for (int j = 0; j < 4; ++j) {
            int grow = mt*128 + rbase + j;
            if (grow < cnt) {
                size_t rowoff = (size_t)(base + grow) * HID;
#pragma unroll
                for (int n = 0; n < 4; ++n) {
                    int col = nbase + wc + n*16 + fr;
                    float v = acc[m][n][j] + b1e[col];
                    float u  = 0.7978845608028654f * (v + 0.044715f * v * v * v);
                    float ex = __expf(2.f * u);
                    float th = 1.f - 2.f / (ex + 1.f);
                    hg[rowoff + col] = f2bf(0.5f * v * (1.f + th));
                }
            }
        }
    }
}

// ---------------- GEMM2: y[tok] += gate * (hg @ w2[e]^T + b2[e]) ----------------
// blockIdx.z = e*2 + ks; each computes a K-half (2048), atomically merged.
__global__ __launch_bounds__(256) void gemm2_kernel(
    const unsigned short* __restrict__ hg,      // M_TOT x H bf16
    const unsigned short* __restrict__ w2b,     // E x D x H bf16
    const float* __restrict__ b2,               // E x D
    const int* __restrict__ rowtok, const float* __restrict__ rowgate,
    const int* __restrict__ counts, const int* __restrict__ offsets,
    float* __restrict__ y)                      // N x D fp32 (pre-zeroed)
{
    int e   = blockIdx.z >> 1;
    int ks  = blockIdx.z & 1;
    int cnt = counts[e];
    int mt  = blockIdx.y;
    if (mt * 128 >= cnt) return;
    int base  = offsets[e];
    int nbase = blockIdx.x * 128;
    int kofs  = ks * (HID/2);

    __shared__ unsigned short As[12288];
    __shared__ unsigned short Bs[12288];

    int tid  = threadIdx.x;
    int lane = tid & 63;
    int wid  = tid >> 6;
    int c0 = wid*2, c1 = wid*2 + 1;
    int sr0 = c0*16 + (lane >> 2);
    int sr1 = c1*16 + (lane >> 2);
    int sgel = (((lane & 3) ^ ((lane >> 3) & 3)) << 3);

    int ar0 = mt*128 + sr0; if (ar0 >= cnt) ar0 = cnt - 1;
    int ar1 = mt*128 + sr1; if (ar1 >= cnt) ar1 = cnt - 1;
    const unsigned short* wE  = w2b + (size_t)e * DIM * HID + kofs;
    const unsigned short* aG0 = hg + (size_t)(base + ar0) * HID + kofs + sgel;
    const unsigned short* aG1 = hg + (size_t)(base + ar1) * HID + kofs + sgel;
    const unsigned short* bG0 = wE + (size_t)(nbase + sr0) * HID + sgel;
    const unsigned short* bG1 = wE + (size_t)(nbase + sr1) * HID + sgel;
    unsigned short* asD0 = &As[c0*512];
    unsigned short* asD1 = &As[c1*512];
    unsigned short* bsD0 = &Bs[c0*512];
    unsigned short* bsD1 = &Bs[c1*512];

    int wr = (wid >> 1) << 6;
    int wc = (wid & 1)  << 6;
    int fr = lane & 15;
    int hi = lane >> 4;
    int g0 = ((hi ^ ((fr >> 1) & 3)) << 3);

    f32x4 acc[4][4];
#pragma unroll
    for (int m = 0; m < 4; ++m)
#pragma unroll
        for (int n = 0; n < 4; ++n)
#pragma unroll
            for (int j = 0; j < 4; ++j) acc[m][n][j] = 0.f;

    kloop<HID/2>(aG0, aG1, bG0, bG1, As, Bs, asD0, asD1, bsD0, bsD1, wr, wc, fr, g0, acc);

    const float* b2e = b2 + (size_t)e * DIM;
#pragma unroll
    for (int m = 0; m < 4; ++m) {
        int rbase = wr + m*16 + hi*4;
#pragma unroll
        for (int j = 0; j < 4; ++j) {
            int grow = mt*128 + rbase + j;
            if (grow < cnt) {
                int tok = rowtok[base + grow];
                float g = rowgate[base + grow];
#pragma unroll
                for (int n = 0; n < 4; ++n) {
                    int col = nbase + wc + n*16 + fr;
                    float v = acc[m][n][j] + (ks == 0 ? b2e[col] : 0.f);
                    atomicAdd(&y[(size_t)tok * DIM + col], g * v);
                }
            }
        }
    }
}

// ---------------- workspace layout ----------------
static constexpr size_t XB_OFF   = 0;
static constexpr size_t W1B_OFF  = XB_OFF  + (size_t)N_TOK * DIM * 2;
static constexpr size_t W2B_OFF  = W1B_OFF + (size_t)NEXP * HID * DIM * 2;
static constexpr size_t HG_OFF   = W2B_OFF + (size_t)NEXP * DIM * HID * 2;
static constexpr size_t RT_OFF   = HG_OFF  + (size_t)M_TOT * HID * 2;
static constexpr size_t RG_OFF   = RT_OFF  + (size_t)M_TOT * 4;
static constexpr size_t TI_OFF   = RG_OFF  + (size_t)M_TOT * 4;
static constexpr size_t TG_OFF   = TI_OFF  + (size_t)N_TOK * TOPK * 4;
static constexpr size_t META_OFF = TG_OFF  + (size_t)N_TOK * TOPK * 4;
static constexpr size_t WS_NEED  = META_OFF + 256;

extern "C" void kernel_launch(void* const* d_in, const int* in_sizes, int n_in,
                              void* d_out, int out_size, void* d_ws, size_t ws_size,
                              hipStream_t stream)
{
    if (ws_size < WS_NEED) return;

    const float* x  = (const float*)d_in[0];
    const float* rw = (const float*)d_in[1];
    const float* rb = (const float*)d_in[2];
    const float* w1 = (const float*)d_in[3];
    const float* b1 = (const float*)d_in[4];
    const float* w2 = (const float*)d_in[5];
    const float* b2 = (const float*)d_in[6];
    float* y = (float*)d_out;

    char* ws = (char*)d_ws;
    unsigned short* xb  = (unsigned short*)(ws + XB_OFF);
    unsigned short* w1b = (unsigned short*)(ws + W1B_OFF);
    unsigned short* w2b = (unsigned short*)(ws + W2B_OFF);
    unsigned short* hg  = (unsigned short*)(ws + HG_OFF);
    int*   rowtok  = (int*)  (ws + RT_OFF);
    float* rowgate = (float*)(ws + RG_OFF);
    int*   tidx    = (int*)  (ws + TI_OFF);
    float* tgate   = (float*)(ws + TG_OFF);
    int*   meta    = (int*)  (ws + META_OFF);
    int* counts  = meta;        // 8 ints
    int* counts2 = meta + 8;    // 8 ints
    int* offsets = meta + 16;   // 8 ints

    hipMemsetAsync(meta, 0, 64, stream);
    hipMemsetAsync(y, 0, (size_t)out_size * 4, stream);

    cvt_kernel<<<2048, 256, 0, stream>>>(w1, w1b, NEXP*HID*DIM/4);
    cvt_kernel<<<2048, 256, 0, stream>>>(w2, w2b, NEXP*DIM*HID/4);

    router_kernel<<<N_TOK, 64, 0, stream>>>(x, rw, rb, xb, tidx, tgate, counts);
    prefix_kernel<<<1, 64, 0, stream>>>(counts, offsets);
    assign_kernel<<<N_TOK/256, 256, 0, stream>>>(tidx, tgate, offsets, counts2, rowtok, rowgate);

    gemm1_kernel<<<dim3(HID/128, 64, NEXP), 256, 0, stream>>>(xb, w1b, b1, rowtok, counts, offsets, hg);
    gemm2_kernel<<<dim3(DIM/128, 64, NEXP*2), 256, 0, stream>>>(hg, w2b, b2, rowtok, rowgate, counts, offsets, y);
}